// Round 21
// baseline (222.902 us; speedup 1.0000x reference)
//
#include <hip/hip_runtime.h>

#define CIN 48
#define COUT 48
#define NPIX 16384  // 128*128
#define XFP 52      // XF pitch in shorts (104 B): bank conflicts 5.8M -> 0.88M (R11/R12)

typedef float f32x4 __attribute__((ext_vector_type(4)));
typedef short bf16x8 __attribute__((ext_vector_type(8)));

__device__ __forceinline__ unsigned short f2bf(float f) {
  unsigned u = __float_as_uint(f);
  unsigned r = (u + 0x7FFFu + ((u >> 16) & 1u)) >> 16;  // RNE
  return (unsigned short)r;
}

// ws layout (floats):
//   w[20736] | ar[128] | ai[128] | pad->21248 | Up[1572864] | yf[786432] | wbf64[13824]
#define OFF_UP     21248
#define OFF_YF     (OFF_UP + CIN * NPIX * 2)
#define OFF_WBF64  (OFF_YF + CIN * NPIX)

// ---------------------------------------------------------------------------
// K1: Gabor weights. f32 w[oc][i][9]; bf16 A-table wbf64[(k*48+oc)*64+i],
//     i pad [48,64) zeroed.
// ---------------------------------------------------------------------------
__global__ __launch_bounds__(256) void gabor_k(
    const float* __restrict__ freq, const float* __restrict__ theta,
    const float* __restrict__ sigma, const float* __restrict__ psi,
    const float* __restrict__ f0, const float* __restrict__ theta0,
    float* __restrict__ wout, unsigned short* __restrict__ wbf64)
{
  int idx = blockIdx.x * 256 + threadIdx.x;
  if (idx < 432 * 16) {
    wbf64[(idx >> 4) * 64 + 48 + (idx & 15)] = 0;
  }
  if (idx >= COUT * CIN * 9) return;
  int k = idx % 9;
  int oi = idx / 9;
  int oc = oi / CIN, ic = oi % CIN;
  int a = k / 3, b = k % 3;
  float Yv = (a == 0) ? -1.0f : ((a == 1) ? 0.5f : 2.0f);
  float Xv = (b == 0) ? -1.0f : ((b == 1) ? 0.5f : 2.0f);
  float th = theta[oi], sg = sigma[oi], fr = freq[oi], ps = psi[oi];
  float F0 = f0[oi], th0 = theta0[oi];
  float c = cosf(th), s = sinf(th);
  float rotx =  Xv * c + Yv * s;
  float roty = -Xv * s + Yv * c;
  float r = sqrtf(rotx * rotx + roty * roty + 0.001f);
  float denom = 2.0f * logf(sg / F0);
  float t1 = (logf(r) - logf(F0)) / denom;
  float g_rad = expf(-t1 * t1);
  float dth = th - th0;
  float g_ang = expf(-dth * dth / (2.0f * sg * sg));
  float g = g_rad * g_ang * cosf(fr * r + ps) / (6.283185307179586f * sg * sg);
  wout[idx] = g;
  wbf64[(k * 48 + oc) * 64 + ic] = f2bf(g);
}

// ---------------------------------------------------------------------------
// K2: circulant band-limit vector
// ---------------------------------------------------------------------------
__global__ void circ_k(float* __restrict__ ar, float* __restrict__ ai)
{
  int d = threadIdx.x;
  float sr = 0.f, si = 0.f;
  for (int u = 34; u < 94; ++u) {
    int m = (u * d) & 127;
    float ang = (float)m * 0.049087385212340526f;
    sr += cosf(ang);
    si += sinf(ang);
  }
  ar[d] = sr * (1.0f / 128.0f);
  ai[d] = si * (1.0f / 128.0f);
}

// ---------------------------------------------------------------------------
// K3a: row band-limit. grid (16, 48): 8 rows per block.
// ---------------------------------------------------------------------------
__global__ __launch_bounds__(256) void stage1_k(
    const float* __restrict__ x, const float* __restrict__ arr,
    const float* __restrict__ aii, float2* __restrict__ Up)
{
  __shared__ float Xs[8 * 128];
  __shared__ float ars[128], ais[128];
  int yg = blockIdx.x, i = blockIdx.y;
  int t = threadIdx.x;
  const float* Xi = x + i * NPIX + yg * 8 * 128;
  for (int p = t; p < 1024; p += 256) Xs[p] = Xi[p];
  if (t < 128) { ars[t] = arr[t]; ais[t] = aii[t]; }
  __syncthreads();
  int j = t & 127;
  int ysl = t >> 7;
  float accr[4], acci[4];
#pragma unroll
  for (int yy = 0; yy < 4; ++yy) { accr[yy] = 0.f; acci[yy] = 0.f; }
  for (int xx = 0; xx < 128; ++xx) {
    float tr = ars[(j - xx) & 127];
    float ti = ais[(j - xx) & 127];
#pragma unroll
    for (int yy = 0; yy < 4; ++yy) {
      float xv = Xs[(ysl * 4 + yy) * 128 + xx];
      accr[yy] += xv * tr;
      acci[yy] += xv * ti;
    }
  }
  float2* UpI = Up + i * NPIX;
  int ybase = yg * 8 + ysl * 4;
#pragma unroll
  for (int yy = 0; yy < 4; ++yy)
    UpI[(ybase + yy) * 128 + j] = make_float2(accr[yy], acci[yy]);
}

// ---------------------------------------------------------------------------
// K3b: column band-limit. grid (16, 48): 8 cols per block. f32 output.
// ---------------------------------------------------------------------------
__global__ __launch_bounds__(256) void stage2_k(
    const float2* __restrict__ Up, const float* __restrict__ arr,
    const float* __restrict__ aii, float* __restrict__ yf)
{
  __shared__ float2 Us[128 * 8];
  __shared__ float ars[128], ais[128];
  int jg = blockIdx.x, i = blockIdx.y;
  int t = threadIdx.x;
  const float2* UpI = Up + i * NPIX;
  for (int p = t; p < 1024; p += 256) {
    int y = p >> 3, jj = p & 7;
    Us[p] = UpI[y * 128 + jg * 8 + jj];
  }
  if (t < 128) { ars[t] = arr[t]; ais[t] = aii[t]; }
  __syncthreads();
  int yp = t & 127;
  int xsl = t >> 7;
  float acc[4];
#pragma unroll
  for (int xx = 0; xx < 4; ++xx) acc[xx] = 0.f;
  for (int y = 0; y < 128; ++y) {
    float tr = ars[(yp - y) & 127];
    float ti = ais[(yp - y) & 127];
#pragma unroll
    for (int xx = 0; xx < 4; ++xx) {
      float2 u = Us[y * 8 + xsl * 4 + xx];
      acc[xx] += u.x * tr - u.y * ti;
    }
  }
  float* yfI = yf + i * NPIX;
  int xb = jg * 8 + xsl * 4;
#pragma unroll
  for (int xx = 0; xx < 4; ++xx)
    yfI[yp * 128 + xb + xx] = acc[xx];
}

// ---------------------------------------------------------------------------
// K4: fused stencil + MFMA GEMM, 16x8 tiles (grid 8x16x48 = 6144 blocks).
//  R18 analysis: LDS (33.7KB -> 4 blocks/CU) was the residency cap, not
//  registers (84 VGPR -> 6 blocks). Halving the tile: LDS = 180x52+16
//  shorts = 18.8KB -> 8 blocks by LDS; residency = min(8, ~6) = 6 blocks
//  = 24 waves/CU (1.5x R18) with NO register-side change ((256,3) proven).
//  Phase 1: 240 tasks (48i x 5sp), ONE per thread, 10 rows x 4 cols,
//  3-row register rotation; interior tiles skip bounds checks.
//  Phase 2: 2 y-rows per wave (acc 24 AGPR), A double-buffered.
//  NaN invariant: pad [48,52) of all 180 rows + 16-short tail zeroed;
//  B1 spill (gq>=2) reads next row's i<16 x A-cols 48..63 = 0, or the
//  row-179 pad/tail (max read offset 9371 < 9376).
// ---------------------------------------------------------------------------
__global__ __launch_bounds__(256, 3) void conv2_k(
    const float* __restrict__ yf, const float* __restrict__ wts,
    const unsigned short* __restrict__ wbf64, float* __restrict__ out)
{
  __shared__ __align__(16) short XF[180 * XFP + 16];

  int o  = blockIdx.z;
  int y0 = blockIdx.y * 8, x0 = blockIdx.x * 16;
  int tid = threadIdx.x;

  // phase 0: zero per-row pad shorts [48,52) and tail (NaN invariant)
  if (tid < 180) *(uint2*)(XF + tid * XFP + 48) = make_uint2(0u, 0u);
  if (tid < 16) XF[180 * XFP + tid] = 0;

  // phase 1: xf(y,x) = sum_{dy,dx in 0..2} w[dy,dx] * yf((y-dy)&127,(x-dx)&127)
  // 240 tasks: i = t/5, sp = t%5; rows rr 0..9 (y = y0-1+rr), cols 4sp+j (<18)
  bool inter = (y0 >= 8) && (y0 <= 112) && (x0 >= 16) && (x0 <= 96);
  if (tid < 240) {
    int i = tid / 5, sp = tid - i * 5;
    const float* Wp = wts + (o * CIN + i) * 9;
    float W0 = Wp[0], W1 = Wp[1], W2 = Wp[2], W3 = Wp[3], W4 = Wp[4],
          W5 = Wp[5], W6 = Wp[6], W7 = Wp[7], W8 = Wp[8];
    const float* yfp = yf + i * NPIX;
    int cb = (x0 - 4 + 4 * sp) & 127;   // mult of 4 -> float4 aligned, wrap-safe
    float Ra[8], Rb[8], Rc[8];

#define LOADROW(dst, ry) { \
    const float* rp_ = yfp + (((ry) & 127) << 7); \
    float4 q0_ = *(const float4*)(rp_ + cb); \
    float4 q1_ = *(const float4*)(rp_ + ((cb + 4) & 127)); \
    dst[0]=q0_.x; dst[1]=q0_.y; dst[2]=q0_.z; dst[3]=q0_.w; \
    dst[4]=q1_.x; dst[5]=q1_.y; dst[6]=q1_.z; dst[7]=q1_.w; }

#define EMIT(rr, R2_, R1_, R0_, CHK) { \
    int y_ = y0 - 1 + (rr); \
    _Pragma("unroll") \
    for (int j = 0; j < 4; ++j) { \
      int cidx_ = 4 * sp + j; \
      if (cidx_ < 18) { \
        float v_ = W0 * R0_[j + 3] + W1 * R0_[j + 2] + W2 * R0_[j + 1] \
                 + W3 * R1_[j + 3] + W4 * R1_[j + 2] + W5 * R1_[j + 1] \
                 + W6 * R2_[j + 3] + W7 * R2_[j + 2] + W8 * R2_[j + 1]; \
        if (CHK) { \
          int xg_ = x0 - 1 + cidx_; \
          if (!((y_ >= 0) && (y_ < 128) && (xg_ >= 0) && (xg_ < 128))) v_ = 0.f; \
        } \
        XF[((rr) * 18 + cidx_) * XFP + i] = (short)f2bf(v_); \
      } } }

#define PH1LOOP(CHK) { \
    LOADROW(Ra, y0 - 3) \
    LOADROW(Rb, y0 - 2) \
    LOADROW(Rc, y0 - 1)  EMIT(0, Ra, Rb, Rc, CHK) \
    LOADROW(Ra, y0 + 0)  EMIT(1, Rb, Rc, Ra, CHK) \
    LOADROW(Rb, y0 + 1)  EMIT(2, Rc, Ra, Rb, CHK) \
    LOADROW(Rc, y0 + 2)  EMIT(3, Ra, Rb, Rc, CHK) \
    LOADROW(Ra, y0 + 3)  EMIT(4, Rb, Rc, Ra, CHK) \
    LOADROW(Rb, y0 + 4)  EMIT(5, Rc, Ra, Rb, CHK) \
    LOADROW(Rc, y0 + 5)  EMIT(6, Ra, Rb, Rc, CHK) \
    LOADROW(Ra, y0 + 6)  EMIT(7, Rb, Rc, Ra, CHK) \
    LOADROW(Rb, y0 + 7)  EMIT(8, Rc, Ra, Rb, CHK) \
    LOADROW(Rc, y0 + 8)  EMIT(9, Ra, Rb, Rc, CHK) }

    if (inter) PH1LOOP(0) else PH1LOOP(1)

#undef LOADROW
#undef EMIT
#undef PH1LOOP
  }
  __syncthreads();

  // phase 2: MFMA GEMM, 4 waves x 2 rows, A double-buffered
  int wv = tid >> 6, lane = tid & 63;
  int tx = lane & 15, gq = lane >> 4;
  f32x4 acc[2][3];
#pragma unroll
  for (int nn = 0; nn < 2; ++nn)
#pragma unroll
    for (int m = 0; m < 3; ++m) acc[nn][m] = (f32x4){0.f, 0.f, 0.f, 0.f};

  const unsigned short* abase = wbf64 + (tx)*64;
  bf16x8 Ac0[3], Ac1[3], An0[3], An1[3];
#pragma unroll
  for (int m = 0; m < 3; ++m) {
    const unsigned short* ap = abase + (m * 16) * 64;
    Ac0[m] = *(const bf16x8*)(ap + gq * 8);
    Ac1[m] = *(const bf16x8*)(ap + 32 + gq * 8);
  }

  for (int k = 0; k < 9; ++k) {
    if (k < 8) {
#pragma unroll
      for (int m = 0; m < 3; ++m) {
        const unsigned short* ap = abase + ((k + 1) * 48 + m * 16) * 64;
        An0[m] = *(const bf16x8*)(ap + gq * 8);
        An1[m] = *(const bf16x8*)(ap + 32 + gq * 8);
      }
    }
    int dy = k / 3, dx = k - dy * 3;
#pragma unroll
    for (int nn = 0; nn < 2; ++nn) {
      int n = wv * 2 + nn;   // output y-row within 8-row tile
      const short* bp = XF + ((n + dy) * 18 + tx + dx) * XFP;  // n+dy in 0..9
      bf16x8 B0 = *(const bf16x8*)(bp + gq * 8);
      bf16x8 B1 = *(const bf16x8*)(bp + 32 + gq * 8);  // pad/next-row/tail, A=0 there
#pragma unroll
      for (int m = 0; m < 3; ++m) {
        acc[nn][m] = __builtin_amdgcn_mfma_f32_16x16x32_bf16(Ac0[m], B0, acc[nn][m], 0, 0, 0);
        acc[nn][m] = __builtin_amdgcn_mfma_f32_16x16x32_bf16(Ac1[m], B1, acc[nn][m], 0, 0, 0);
      }
    }
#pragma unroll
    for (int m = 0; m < 3; ++m) { Ac0[m] = An0[m]; Ac1[m] = An1[m]; }
  }

  // epilogue: C frag col=lane&15 (pixel x), row=gq*4+r (oc)
#pragma unroll
  for (int nn = 0; nn < 2; ++nn) {
    int y = y0 + wv * 2 + nn;
#pragma unroll
    for (int m = 0; m < 3; ++m) {
#pragma unroll
      for (int r = 0; r < 4; ++r) {
        int oc = m * 16 + gq * 4 + r;
        out[((size_t)(o * COUT + oc) << 14) + (y << 7) + x0 + tx] = acc[nn][m][r];
      }
    }
  }
}

// ---------------------------------------------------------------------------
extern "C" void kernel_launch(void* const* d_in, const int* in_sizes, int n_in,
                              void* d_out, int out_size, void* d_ws, size_t ws_size,
                              hipStream_t stream)
{
  const float* x      = (const float*)d_in[0];
  const float* freq   = (const float*)d_in[1];
  const float* theta  = (const float*)d_in[2];
  const float* sigma  = (const float*)d_in[3];
  const float* psi    = (const float*)d_in[4];
  const float* f0     = (const float*)d_in[5];
  const float* theta0 = (const float*)d_in[6];
  float* out = (float*)d_out;
  float* ws  = (float*)d_ws;

  float*  w     = ws;
  float*  ar    = ws + 20736;
  float*  ai    = ws + 20864;
  float2* Up    = (float2*)(ws + OFF_UP);
  float*  yf    = ws + OFF_YF;
  unsigned short* wbf64 = (unsigned short*)(ws + OFF_WBF64);

  gabor_k<<<dim3(81), dim3(256), 0, stream>>>(freq, theta, sigma, psi, f0, theta0, w, wbf64);
  circ_k<<<dim3(1), dim3(128), 0, stream>>>(ar, ai);
  stage1_k<<<dim3(16, 48), dim3(256), 0, stream>>>(x, ar, ai, Up);
  stage2_k<<<dim3(16, 48), dim3(256), 0, stream>>>(Up, ar, ai, yf);
  conv2_k<<<dim3(8, 16, 48), dim3(256), 0, stream>>>(yf, w, wbf64, out);
}

// Round 22
// 159.651 us; speedup vs baseline: 1.3962x; 1.3962x over previous
//
#include <hip/hip_runtime.h>

#define CIN 48
#define COUT 48
#define NPIX 16384  // 128*128
#define XFP 52      // XF pitch in shorts (104 B): bank conflicts 5.8M -> 0.88M (R11/R12)
#define YROW 6144   // 48*128: yf stored [y][i][x] (transposed for conv2 locality)

typedef float f32x4 __attribute__((ext_vector_type(4)));
typedef short bf16x8 __attribute__((ext_vector_type(8)));

__device__ __forceinline__ unsigned short f2bf(float f) {
  unsigned u = __float_as_uint(f);
  unsigned r = (u + 0x7FFFu + ((u >> 16) & 1u)) >> 16;  // RNE
  return (unsigned short)r;
}

// ws layout (floats):
//   w[20736] | ar[128] | ai[128] | pad->21248 | Up[1572864] | yf[786432] | wbf64[13824]
#define OFF_UP     21248
#define OFF_YF     (OFF_UP + CIN * NPIX * 2)
#define OFF_WBF64  (OFF_YF + CIN * NPIX)

// ---------------------------------------------------------------------------
// K1: Gabor weights. f32 w[oc][i][9]; bf16 A-table wbf64[(k*48+oc)*64+i],
//     i pad [48,64) zeroed.
// ---------------------------------------------------------------------------
__global__ __launch_bounds__(256) void gabor_k(
    const float* __restrict__ freq, const float* __restrict__ theta,
    const float* __restrict__ sigma, const float* __restrict__ psi,
    const float* __restrict__ f0, const float* __restrict__ theta0,
    float* __restrict__ wout, unsigned short* __restrict__ wbf64)
{
  int idx = blockIdx.x * 256 + threadIdx.x;
  if (idx < 432 * 16) {
    wbf64[(idx >> 4) * 64 + 48 + (idx & 15)] = 0;
  }
  if (idx >= COUT * CIN * 9) return;
  int k = idx % 9;
  int oi = idx / 9;
  int oc = oi / CIN, ic = oi % CIN;
  int a = k / 3, b = k % 3;
  float Yv = (a == 0) ? -1.0f : ((a == 1) ? 0.5f : 2.0f);
  float Xv = (b == 0) ? -1.0f : ((b == 1) ? 0.5f : 2.0f);
  float th = theta[oi], sg = sigma[oi], fr = freq[oi], ps = psi[oi];
  float F0 = f0[oi], th0 = theta0[oi];
  float c = cosf(th), s = sinf(th);
  float rotx =  Xv * c + Yv * s;
  float roty = -Xv * s + Yv * c;
  float r = sqrtf(rotx * rotx + roty * roty + 0.001f);
  float denom = 2.0f * logf(sg / F0);
  float t1 = (logf(r) - logf(F0)) / denom;
  float g_rad = expf(-t1 * t1);
  float dth = th - th0;
  float g_ang = expf(-dth * dth / (2.0f * sg * sg));
  float g = g_rad * g_ang * cosf(fr * r + ps) / (6.283185307179586f * sg * sg);
  wout[idx] = g;
  wbf64[(k * 48 + oc) * 64 + ic] = f2bf(g);
}

// ---------------------------------------------------------------------------
// K2: circulant band-limit vector
// ---------------------------------------------------------------------------
__global__ void circ_k(float* __restrict__ ar, float* __restrict__ ai)
{
  int d = threadIdx.x;
  float sr = 0.f, si = 0.f;
  for (int u = 34; u < 94; ++u) {
    int m = (u * d) & 127;
    float ang = (float)m * 0.049087385212340526f;
    sr += cosf(ang);
    si += sinf(ang);
  }
  ar[d] = sr * (1.0f / 128.0f);
  ai[d] = si * (1.0f / 128.0f);
}

// ---------------------------------------------------------------------------
// K3a: row band-limit. grid (16, 48): 8 rows per block.
// ---------------------------------------------------------------------------
__global__ __launch_bounds__(256) void stage1_k(
    const float* __restrict__ x, const float* __restrict__ arr,
    const float* __restrict__ aii, float2* __restrict__ Up)
{
  __shared__ float Xs[8 * 128];
  __shared__ float ars[128], ais[128];
  int yg = blockIdx.x, i = blockIdx.y;
  int t = threadIdx.x;
  const float* Xi = x + i * NPIX + yg * 8 * 128;
  for (int p = t; p < 1024; p += 256) Xs[p] = Xi[p];
  if (t < 128) { ars[t] = arr[t]; ais[t] = aii[t]; }
  __syncthreads();
  int j = t & 127;
  int ysl = t >> 7;
  float accr[4], acci[4];
#pragma unroll
  for (int yy = 0; yy < 4; ++yy) { accr[yy] = 0.f; acci[yy] = 0.f; }
  for (int xx = 0; xx < 128; ++xx) {
    float tr = ars[(j - xx) & 127];
    float ti = ais[(j - xx) & 127];
#pragma unroll
    for (int yy = 0; yy < 4; ++yy) {
      float xv = Xs[(ysl * 4 + yy) * 128 + xx];
      accr[yy] += xv * tr;
      acci[yy] += xv * ti;
    }
  }
  float2* UpI = Up + i * NPIX;
  int ybase = yg * 8 + ysl * 4;
#pragma unroll
  for (int yy = 0; yy < 4; ++yy)
    UpI[(ybase + yy) * 128 + j] = make_float2(accr[yy], acci[yy]);
}

// ---------------------------------------------------------------------------
// K3b: column band-limit. grid (16, 48): 8 cols per block. f32 output,
//  TRANSPOSED layout yf[y][i][x] (conv2 phase-1 wave footprint becomes
//  13 x 512B segments in one 24KB row-slab instead of 13 x 64KB-apart pages).
// ---------------------------------------------------------------------------
__global__ __launch_bounds__(256) void stage2_k(
    const float2* __restrict__ Up, const float* __restrict__ arr,
    const float* __restrict__ aii, float* __restrict__ yf)
{
  __shared__ float2 Us[128 * 8];
  __shared__ float ars[128], ais[128];
  int jg = blockIdx.x, i = blockIdx.y;
  int t = threadIdx.x;
  const float2* UpI = Up + i * NPIX;
  for (int p = t; p < 1024; p += 256) {
    int y = p >> 3, jj = p & 7;
    Us[p] = UpI[y * 128 + jg * 8 + jj];
  }
  if (t < 128) { ars[t] = arr[t]; ais[t] = aii[t]; }
  __syncthreads();
  int yp = t & 127;
  int xsl = t >> 7;
  float acc[4];
#pragma unroll
  for (int xx = 0; xx < 4; ++xx) acc[xx] = 0.f;
  for (int y = 0; y < 128; ++y) {
    float tr = ars[(yp - y) & 127];
    float ti = ais[(yp - y) & 127];
#pragma unroll
    for (int xx = 0; xx < 4; ++xx) {
      float2 u = Us[y * 8 + xsl * 4 + xx];
      acc[xx] += u.x * tr - u.y * ti;
    }
  }
  int xb = jg * 8 + xsl * 4;
#pragma unroll
  for (int xx = 0; xx < 4; ++xx)
    yf[(yp * 48 + i) * 128 + xb + xx] = acc[xx];   // [y][i][x]
}

// ---------------------------------------------------------------------------
// K4 (R18 structure verbatim, yf indexed as [y][i][x]):
//  fused stencil + MFMA GEMM, (256,3) = proven 84-VGPR no-spill equilibrium
//  (every occupancy lever -- (256,4/5), 512-thread, slice, small-tile --
//  made the allocator shrink the file to 44-64 and serialize/spill).
//  LDS: XF[324 px][52 shorts] + 16-short zero tail = 33728 B.
//  NaN invariant: pad [48,52) + tail zeroed; B1 spill reads -> next row's
//  i<16 x A-cols 48..63 = 0, or row 323 -> zeroed tail.
//  Phase 1: 480 half-strip tasks, threads 0..239 run 2 interleaved;
//  interior tiles (x0,y0 in [16,96]) skip bounds checks (wave-uniform).
//  Phase 2: 16x16x32_bf16 only; A zero-padded i>=48; A double-buffered.
// ---------------------------------------------------------------------------
__global__ __launch_bounds__(256, 3) void conv2_k(
    const float* __restrict__ yf, const float* __restrict__ wts,
    const unsigned short* __restrict__ wbf64, float* __restrict__ out)
{
  __shared__ __align__(16) short XF[324 * XFP + 16];

  int o  = blockIdx.z;
  int y0 = blockIdx.y * 16, x0 = blockIdx.x * 16;
  int tid = threadIdx.x;

  // phase 0: zero per-row pad shorts [48,52) and tail (NaN invariant)
  for (int p = tid; p < 324; p += 256)
    *(uint2*)(XF + p * XFP + 48) = make_uint2(0u, 0u);
  if (tid < 16) XF[324 * XFP + tid] = 0;

  // phase 1: xf(y,x) = sum_{dy,dx in 0..2} w[dy,dx] * yf((y-dy)&127,(x-dx)&127)
  bool inter = (y0 >= 16) && (y0 <= 96) && (x0 >= 16) && (x0 <= 96);
  if (tid < 240) {
    int sA = tid, sB = tid + 240;
    int iA = sA / 10, rA = sA - iA * 10, spA = rA % 5, hA = rA / 5;
    int iB = sB / 10, rB = sB - iB * 10, spB = rB % 5, hB = rB / 5;
    const float* WpA = wts + (o * CIN + iA) * 9;
    const float* WpB = wts + (o * CIN + iB) * 9;
    float WA0 = WpA[0], WA1 = WpA[1], WA2 = WpA[2], WA3 = WpA[3], WA4 = WpA[4],
          WA5 = WpA[5], WA6 = WpA[6], WA7 = WpA[7], WA8 = WpA[8];
    float WB0 = WpB[0], WB1 = WpB[1], WB2 = WpB[2], WB3 = WpB[3], WB4 = WpB[4],
          WB5 = WpB[5], WB6 = WpB[6], WB7 = WpB[7], WB8 = WpB[8];
    const float* yfA = yf + iA * 128;   // [y][i][x]: plane base = i*128
    const float* yfB = yf + iB * 128;
    int cbA = (x0 - 4 + 4 * spA) & 127;   // mult of 4 -> float4 aligned, wrap-safe
    int cbB = (x0 - 4 + 4 * spB) & 127;
    int rbA = hA * 9, rbB = hB * 9;
    float RaA[8], RbA[8], RcA[8], RaB[8], RbB[8], RcB[8];

#define LOADA(dst, ry) { \
    const float* rp_ = yfA + ((ry) & 127) * YROW; \
    float4 q0_ = *(const float4*)(rp_ + cbA); \
    float4 q1_ = *(const float4*)(rp_ + ((cbA + 4) & 127)); \
    dst[0]=q0_.x; dst[1]=q0_.y; dst[2]=q0_.z; dst[3]=q0_.w; \
    dst[4]=q1_.x; dst[5]=q1_.y; dst[6]=q1_.z; dst[7]=q1_.w; }
#define LOADB(dst, ry) { \
    const float* rp_ = yfB + ((ry) & 127) * YROW; \
    float4 q0_ = *(const float4*)(rp_ + cbB); \
    float4 q1_ = *(const float4*)(rp_ + ((cbB + 4) & 127)); \
    dst[0]=q0_.x; dst[1]=q0_.y; dst[2]=q0_.z; dst[3]=q0_.w; \
    dst[4]=q1_.x; dst[5]=q1_.y; dst[6]=q1_.z; dst[7]=q1_.w; }

#define EMITA(rr, R2_, R1_, R0_, CHK) { \
    int y_ = y0 - 1 + (rr); \
    _Pragma("unroll") \
    for (int j = 0; j < 4; ++j) { \
      int cidx_ = 4 * spA + j; \
      if (cidx_ < 18) { \
        float v_ = WA0 * R0_[j + 3] + WA1 * R0_[j + 2] + WA2 * R0_[j + 1] \
                 + WA3 * R1_[j + 3] + WA4 * R1_[j + 2] + WA5 * R1_[j + 1] \
                 + WA6 * R2_[j + 3] + WA7 * R2_[j + 2] + WA8 * R2_[j + 1]; \
        if (CHK) { \
          int xg_ = x0 - 1 + cidx_; \
          if (!((y_ >= 0) && (y_ < 128) && (xg_ >= 0) && (xg_ < 128))) v_ = 0.f; \
        } \
        XF[((rr) * 18 + cidx_) * XFP + iA] = (short)f2bf(v_); \
      } } }
#define EMITB(rr, R2_, R1_, R0_, CHK) { \
    int y_ = y0 - 1 + (rr); \
    _Pragma("unroll") \
    for (int j = 0; j < 4; ++j) { \
      int cidx_ = 4 * spB + j; \
      if (cidx_ < 18) { \
        float v_ = WB0 * R0_[j + 3] + WB1 * R0_[j + 2] + WB2 * R0_[j + 1] \
                 + WB3 * R1_[j + 3] + WB4 * R1_[j + 2] + WB5 * R1_[j + 1] \
                 + WB6 * R2_[j + 3] + WB7 * R2_[j + 2] + WB8 * R2_[j + 1]; \
        if (CHK) { \
          int xg_ = x0 - 1 + cidx_; \
          if (!((y_ >= 0) && (y_ < 128) && (xg_ >= 0) && (xg_ < 128))) v_ = 0.f; \
        } \
        XF[((rr) * 18 + cidx_) * XFP + iB] = (short)f2bf(v_); \
      } } }

#define PH1LOOP(CHK) { \
    LOADA(RaA, y0 - 3 + rbA)  LOADB(RaB, y0 - 3 + rbB) \
    LOADA(RbA, y0 - 2 + rbA)  LOADB(RbB, y0 - 2 + rbB) \
    _Pragma("unroll") \
    for (int rr0 = 0; rr0 < 9; rr0 += 3) { \
      LOADA(RcA, y0 - 1 + rbA + rr0)  LOADB(RcB, y0 - 1 + rbB + rr0) \
      EMITA(rbA + rr0,     RaA, RbA, RcA, CHK)  EMITB(rbB + rr0,     RaB, RbB, RcB, CHK) \
      LOADA(RaA, y0 + rbA + rr0)      LOADB(RaB, y0 + rbB + rr0) \
      EMITA(rbA + rr0 + 1, RbA, RcA, RaA, CHK)  EMITB(rbB + rr0 + 1, RbB, RcB, RaB, CHK) \
      LOADA(RbA, y0 + 1 + rbA + rr0)  LOADB(RbB, y0 + 1 + rbB + rr0) \
      EMITA(rbA + rr0 + 2, RcA, RaA, RbA, CHK)  EMITB(rbB + rr0 + 2, RcB, RaB, RbB, CHK) \
    } }

    if (inter) PH1LOOP(0) else PH1LOOP(1)

#undef LOADA
#undef LOADB
#undef EMITA
#undef EMITB
#undef PH1LOOP
  }
  __syncthreads();

  // phase 2: MFMA GEMM, 16x16x32_bf16 only, A double-buffered
  int wv = tid >> 6, lane = tid & 63;
  int tx = lane & 15, gq = lane >> 4;
  f32x4 acc[4][3];
#pragma unroll
  for (int nn = 0; nn < 4; ++nn)
#pragma unroll
    for (int m = 0; m < 3; ++m) acc[nn][m] = (f32x4){0.f, 0.f, 0.f, 0.f};

  const unsigned short* abase = wbf64 + (tx)*64;
  bf16x8 Ac0[3], Ac1[3], An0[3], An1[3];
#pragma unroll
  for (int m = 0; m < 3; ++m) {
    const unsigned short* ap = abase + (m * 16) * 64;
    Ac0[m] = *(const bf16x8*)(ap + gq * 8);
    Ac1[m] = *(const bf16x8*)(ap + 32 + gq * 8);
  }

  for (int k = 0; k < 9; ++k) {
    if (k < 8) {
#pragma unroll
      for (int m = 0; m < 3; ++m) {
        const unsigned short* ap = abase + ((k + 1) * 48 + m * 16) * 64;
        An0[m] = *(const bf16x8*)(ap + gq * 8);
        An1[m] = *(const bf16x8*)(ap + 32 + gq * 8);
      }
    }
    int dy = k / 3, dx = k - dy * 3;
#pragma unroll
    for (int nn = 0; nn < 4; ++nn) {
      int n = wv * 4 + nn;
      const short* bp = XF + ((n + dy) * 18 + tx + dx) * XFP;
      bf16x8 B0 = *(const bf16x8*)(bp + gq * 8);
      bf16x8 B1 = *(const bf16x8*)(bp + 32 + gq * 8);  // pad/next-row, A=0 there
#pragma unroll
      for (int m = 0; m < 3; ++m) {
        acc[nn][m] = __builtin_amdgcn_mfma_f32_16x16x32_bf16(Ac0[m], B0, acc[nn][m], 0, 0, 0);
        acc[nn][m] = __builtin_amdgcn_mfma_f32_16x16x32_bf16(Ac1[m], B1, acc[nn][m], 0, 0, 0);
      }
    }
#pragma unroll
    for (int m = 0; m < 3; ++m) { Ac0[m] = An0[m]; Ac1[m] = An1[m]; }
  }

  // epilogue: C frag col=lane&15 (pixel x), row=gq*4+r (oc)
#pragma unroll
  for (int nn = 0; nn < 4; ++nn) {
    int y = y0 + wv * 4 + nn;
#pragma unroll
    for (int m = 0; m < 3; ++m) {
#pragma unroll
      for (int r = 0; r < 4; ++r) {
        int oc = m * 16 + gq * 4 + r;
        out[((size_t)(o * COUT + oc) << 14) + (y << 7) + x0 + tx] = acc[nn][m][r];
      }
    }
  }
}

// ---------------------------------------------------------------------------
extern "C" void kernel_launch(void* const* d_in, const int* in_sizes, int n_in,
                              void* d_out, int out_size, void* d_ws, size_t ws_size,
                              hipStream_t stream)
{
  const float* x      = (const float*)d_in[0];
  const float* freq   = (const float*)d_in[1];
  const float* theta  = (const float*)d_in[2];
  const float* sigma  = (const float*)d_in[3];
  const float* psi    = (const float*)d_in[4];
  const float* f0     = (const float*)d_in[5];
  const float* theta0 = (const float*)d_in[6];
  float* out = (float*)d_out;
  float* ws  = (float*)d_ws;

  float*  w     = ws;
  float*  ar    = ws + 20736;
  float*  ai    = ws + 20864;
  float2* Up    = (float2*)(ws + OFF_UP);
  float*  yf    = ws + OFF_YF;
  unsigned short* wbf64 = (unsigned short*)(ws + OFF_WBF64);

  gabor_k<<<dim3(81), dim3(256), 0, stream>>>(freq, theta, sigma, psi, f0, theta0, w, wbf64);
  circ_k<<<dim3(1), dim3(128), 0, stream>>>(ar, ai);
  stage1_k<<<dim3(16, 48), dim3(256), 0, stream>>>(x, ar, ai, Up);
  stage2_k<<<dim3(16, 48), dim3(256), 0, stream>>>(Up, ar, ai, yf);
  conv2_k<<<dim3(8, 8, 48), dim3(256), 0, stream>>>(yf, w, wbf64, out);
}

// Round 23
// 156.167 us; speedup vs baseline: 1.4273x; 1.0223x over previous
//
#include <hip/hip_runtime.h>

#define CIN 48
#define COUT 48
#define NPIX 16384  // 128*128
#define XFP 52      // XF pitch in shorts (104 B): bank conflicts 5.8M -> 0.88M (R11/R12)
#define YROW 6144   // 48*128: yf stored [y][i][x]

typedef float f32x4 __attribute__((ext_vector_type(4)));
typedef short bf16x8 __attribute__((ext_vector_type(8)));

__device__ __forceinline__ unsigned short f2bf(float f) {
  unsigned u = __float_as_uint(f);
  unsigned r = (u + 0x7FFFu + ((u >> 16) & 1u)) >> 16;  // RNE
  return (unsigned short)r;
}

// packed f32x2 -> bf16x2 in one VALU op (gfx950; no builtin -- inline asm)
__device__ __forceinline__ unsigned cvtpk_bf16(float lo, float hi) {
  unsigned r;
  asm("v_cvt_pk_bf16_f32 %0, %1, %2" : "=v"(r) : "v"(lo), "v"(hi));
  return r;
}

// ws layout (floats):
//   w[20736] | ar[128] | ai[128] | pad->21248 | Up[1572864] | yf[786432] | wbf64[13824]
#define OFF_UP     21248
#define OFF_YF     (OFF_UP + CIN * NPIX * 2)
#define OFF_WBF64  (OFF_YF + CIN * NPIX)

// ---------------------------------------------------------------------------
// K1: Gabor weights. f32 w[oc][i][9]; bf16 A-table wbf64[(k*48+oc)*64+i],
//     i pad [48,64) zeroed.
// ---------------------------------------------------------------------------
__global__ __launch_bounds__(256) void gabor_k(
    const float* __restrict__ freq, const float* __restrict__ theta,
    const float* __restrict__ sigma, const float* __restrict__ psi,
    const float* __restrict__ f0, const float* __restrict__ theta0,
    float* __restrict__ wout, unsigned short* __restrict__ wbf64)
{
  int idx = blockIdx.x * 256 + threadIdx.x;
  if (idx < 432 * 16) {
    wbf64[(idx >> 4) * 64 + 48 + (idx & 15)] = 0;
  }
  if (idx >= COUT * CIN * 9) return;
  int k = idx % 9;
  int oi = idx / 9;
  int oc = oi / CIN, ic = oi % CIN;
  int a = k / 3, b = k % 3;
  float Yv = (a == 0) ? -1.0f : ((a == 1) ? 0.5f : 2.0f);
  float Xv = (b == 0) ? -1.0f : ((b == 1) ? 0.5f : 2.0f);
  float th = theta[oi], sg = sigma[oi], fr = freq[oi], ps = psi[oi];
  float F0 = f0[oi], th0 = theta0[oi];
  float c = cosf(th), s = sinf(th);
  float rotx =  Xv * c + Yv * s;
  float roty = -Xv * s + Yv * c;
  float r = sqrtf(rotx * rotx + roty * roty + 0.001f);
  float denom = 2.0f * logf(sg / F0);
  float t1 = (logf(r) - logf(F0)) / denom;
  float g_rad = expf(-t1 * t1);
  float dth = th - th0;
  float g_ang = expf(-dth * dth / (2.0f * sg * sg));
  float g = g_rad * g_ang * cosf(fr * r + ps) / (6.283185307179586f * sg * sg);
  wout[idx] = g;
  wbf64[(k * 48 + oc) * 64 + ic] = f2bf(g);
}

// ---------------------------------------------------------------------------
// K2: circulant band-limit vector
// ---------------------------------------------------------------------------
__global__ void circ_k(float* __restrict__ ar, float* __restrict__ ai)
{
  int d = threadIdx.x;
  float sr = 0.f, si = 0.f;
  for (int u = 34; u < 94; ++u) {
    int m = (u * d) & 127;
    float ang = (float)m * 0.049087385212340526f;
    sr += cosf(ang);
    si += sinf(ang);
  }
  ar[d] = sr * (1.0f / 128.0f);
  ai[d] = si * (1.0f / 128.0f);
}

// ---------------------------------------------------------------------------
// K3a: row band-limit. grid (16, 48): 8 rows per block.
// ---------------------------------------------------------------------------
__global__ __launch_bounds__(256) void stage1_k(
    const float* __restrict__ x, const float* __restrict__ arr,
    const float* __restrict__ aii, float2* __restrict__ Up)
{
  __shared__ float Xs[8 * 128];
  __shared__ float ars[128], ais[128];
  int yg = blockIdx.x, i = blockIdx.y;
  int t = threadIdx.x;
  const float* Xi = x + i * NPIX + yg * 8 * 128;
  for (int p = t; p < 1024; p += 256) Xs[p] = Xi[p];
  if (t < 128) { ars[t] = arr[t]; ais[t] = aii[t]; }
  __syncthreads();
  int j = t & 127;
  int ysl = t >> 7;
  float accr[4], acci[4];
#pragma unroll
  for (int yy = 0; yy < 4; ++yy) { accr[yy] = 0.f; acci[yy] = 0.f; }
  for (int xx = 0; xx < 128; ++xx) {
    float tr = ars[(j - xx) & 127];
    float ti = ais[(j - xx) & 127];
#pragma unroll
    for (int yy = 0; yy < 4; ++yy) {
      float xv = Xs[(ysl * 4 + yy) * 128 + xx];
      accr[yy] += xv * tr;
      acci[yy] += xv * ti;
    }
  }
  float2* UpI = Up + i * NPIX;
  int ybase = yg * 8 + ysl * 4;
#pragma unroll
  for (int yy = 0; yy < 4; ++yy)
    UpI[(ybase + yy) * 128 + j] = make_float2(accr[yy], acci[yy]);
}

// ---------------------------------------------------------------------------
// K3b: column band-limit. grid (16, 48): 8 cols per block. f32 output,
//  transposed layout yf[y][i][x].
// ---------------------------------------------------------------------------
__global__ __launch_bounds__(256) void stage2_k(
    const float2* __restrict__ Up, const float* __restrict__ arr,
    const float* __restrict__ aii, float* __restrict__ yf)
{
  __shared__ float2 Us[128 * 8];
  __shared__ float ars[128], ais[128];
  int jg = blockIdx.x, i = blockIdx.y;
  int t = threadIdx.x;
  const float2* UpI = Up + i * NPIX;
  for (int p = t; p < 1024; p += 256) {
    int y = p >> 3, jj = p & 7;
    Us[p] = UpI[y * 128 + jg * 8 + jj];
  }
  if (t < 128) { ars[t] = arr[t]; ais[t] = aii[t]; }
  __syncthreads();
  int yp = t & 127;
  int xsl = t >> 7;
  float acc[4];
#pragma unroll
  for (int xx = 0; xx < 4; ++xx) acc[xx] = 0.f;
  for (int y = 0; y < 128; ++y) {
    float tr = ars[(yp - y) & 127];
    float ti = ais[(yp - y) & 127];
#pragma unroll
    for (int xx = 0; xx < 4; ++xx) {
      float2 u = Us[y * 8 + xsl * 4 + xx];
      acc[xx] += u.x * tr - u.y * ti;
    }
  }
  int xb = jg * 8 + xsl * 4;
#pragma unroll
  for (int xx = 0; xx < 4; ++xx)
    yf[(yp * 48 + i) * 128 + xb + xx] = acc[xx];   // [y][i][x]
}

// ---------------------------------------------------------------------------
// K4 (R22 structure; EMIT bf16-convert via v_cvt_pk_bf16_f32):
//  fused stencil + MFMA GEMM, (256,3) = proven 84-VGPR no-spill equilibrium.
//  LDS: XF[324 px][52 shorts] + 16-short zero tail = 33728 B.
//  NaN invariant: pad [48,52) + tail zeroed; B1 spill reads -> next row's
//  i<16 x A-cols 48..63 = 0, or row 323 -> zeroed tail.
//  Phase 1: 480 half-strip tasks, threads 0..239 run 2 interleaved;
//  interior tiles skip bounds checks. bf16 conversion: 1 cvt_pk per 2 px
//  (replaces ~4-5 VALU/px of hand-rolled RNE -- ~20% of phase-1 VALU).
//  Phase 2: 16x16x32_bf16 only; A zero-padded i>=48; A double-buffered.
// ---------------------------------------------------------------------------
__global__ __launch_bounds__(256, 3) void conv2_k(
    const float* __restrict__ yf, const float* __restrict__ wts,
    const unsigned short* __restrict__ wbf64, float* __restrict__ out)
{
  __shared__ __align__(16) short XF[324 * XFP + 16];

  int o  = blockIdx.z;
  int y0 = blockIdx.y * 16, x0 = blockIdx.x * 16;
  int tid = threadIdx.x;

  // phase 0: zero per-row pad shorts [48,52) and tail (NaN invariant)
  for (int p = tid; p < 324; p += 256)
    *(uint2*)(XF + p * XFP + 48) = make_uint2(0u, 0u);
  if (tid < 16) XF[324 * XFP + tid] = 0;

  // phase 1: xf(y,x) = sum_{dy,dx in 0..2} w[dy,dx] * yf((y-dy)&127,(x-dx)&127)
  bool inter = (y0 >= 16) && (y0 <= 96) && (x0 >= 16) && (x0 <= 96);
  if (tid < 240) {
    int sA = tid, sB = tid + 240;
    int iA = sA / 10, rA = sA - iA * 10, spA = rA % 5, hA = rA / 5;
    int iB = sB / 10, rB = sB - iB * 10, spB = rB % 5, hB = rB / 5;
    const float* WpA = wts + (o * CIN + iA) * 9;
    const float* WpB = wts + (o * CIN + iB) * 9;
    float WA0 = WpA[0], WA1 = WpA[1], WA2 = WpA[2], WA3 = WpA[3], WA4 = WpA[4],
          WA5 = WpA[5], WA6 = WpA[6], WA7 = WpA[7], WA8 = WpA[8];
    float WB0 = WpB[0], WB1 = WpB[1], WB2 = WpB[2], WB3 = WpB[3], WB4 = WpB[4],
          WB5 = WpB[5], WB6 = WpB[6], WB7 = WpB[7], WB8 = WpB[8];
    const float* yfA = yf + iA * 128;   // [y][i][x]: plane base = i*128
    const float* yfB = yf + iB * 128;
    int cbA = (x0 - 4 + 4 * spA) & 127;
    int cbB = (x0 - 4 + 4 * spB) & 127;
    int rbA = hA * 9, rbB = hB * 9;
    float RaA[8], RbA[8], RcA[8], RaB[8], RbB[8], RcB[8];

#define LOADA(dst, ry) { \
    const float* rp_ = yfA + ((ry) & 127) * YROW; \
    float4 q0_ = *(const float4*)(rp_ + cbA); \
    float4 q1_ = *(const float4*)(rp_ + ((cbA + 4) & 127)); \
    dst[0]=q0_.x; dst[1]=q0_.y; dst[2]=q0_.z; dst[3]=q0_.w; \
    dst[4]=q1_.x; dst[5]=q1_.y; dst[6]=q1_.z; dst[7]=q1_.w; }
#define LOADB(dst, ry) { \
    const float* rp_ = yfB + ((ry) & 127) * YROW; \
    float4 q0_ = *(const float4*)(rp_ + cbB); \
    float4 q1_ = *(const float4*)(rp_ + ((cbB + 4) & 127)); \
    dst[0]=q0_.x; dst[1]=q0_.y; dst[2]=q0_.z; dst[3]=q0_.w; \
    dst[4]=q1_.x; dst[5]=q1_.y; dst[6]=q1_.z; dst[7]=q1_.w; }

// compute 4 px, pack 2x cvt_pk, store the (cidx<18) ones
#define EMITG(rr, R2_, R1_, R0_, W0_,W1_,W2_,W3_,W4_,W5_,W6_,W7_,W8_, SP_, II_, CHK) { \
    int y_ = y0 - 1 + (rr); \
    float v_[4]; \
    _Pragma("unroll") \
    for (int j = 0; j < 4; ++j) { \
      v_[j] = W0_ * R0_[j + 3] + W1_ * R0_[j + 2] + W2_ * R0_[j + 1] \
            + W3_ * R1_[j + 3] + W4_ * R1_[j + 2] + W5_ * R1_[j + 1] \
            + W6_ * R2_[j + 3] + W7_ * R2_[j + 2] + W8_ * R2_[j + 1]; \
      if (CHK) { \
        int xg_ = x0 - 1 + 4 * SP_ + j; \
        if (!((y_ >= 0) && (y_ < 128) && (xg_ >= 0) && (xg_ < 128))) v_[j] = 0.f; \
      } \
    } \
    unsigned p01_ = cvtpk_bf16(v_[0], v_[1]); \
    unsigned p23_ = cvtpk_bf16(v_[2], v_[3]); \
    short* base_ = XF + ((rr) * 18 + 4 * SP_) * XFP + II_; \
    base_[0]       = (short)(p01_ & 0xffffu); \
    base_[XFP]     = (short)(p01_ >> 16); \
    if (4 * SP_ + 2 < 18) { \
      base_[2 * XFP] = (short)(p23_ & 0xffffu); \
      base_[3 * XFP] = (short)(p23_ >> 16); \
    } }

#define EMITA(rr, R2_, R1_, R0_, CHK) \
    EMITG(rr, R2_, R1_, R0_, WA0,WA1,WA2,WA3,WA4,WA5,WA6,WA7,WA8, spA, iA, CHK)
#define EMITB(rr, R2_, R1_, R0_, CHK) \
    EMITG(rr, R2_, R1_, R0_, WB0,WB1,WB2,WB3,WB4,WB5,WB6,WB7,WB8, spB, iB, CHK)

#define PH1LOOP(CHK) { \
    LOADA(RaA, y0 - 3 + rbA)  LOADB(RaB, y0 - 3 + rbB) \
    LOADA(RbA, y0 - 2 + rbA)  LOADB(RbB, y0 - 2 + rbB) \
    _Pragma("unroll") \
    for (int rr0 = 0; rr0 < 9; rr0 += 3) { \
      LOADA(RcA, y0 - 1 + rbA + rr0)  LOADB(RcB, y0 - 1 + rbB + rr0) \
      EMITA(rbA + rr0,     RaA, RbA, RcA, CHK)  EMITB(rbB + rr0,     RaB, RbB, RcB, CHK) \
      LOADA(RaA, y0 + rbA + rr0)      LOADB(RaB, y0 + rbB + rr0) \
      EMITA(rbA + rr0 + 1, RbA, RcA, RaA, CHK)  EMITB(rbB + rr0 + 1, RbB, RcB, RaB, CHK) \
      LOADA(RbA, y0 + 1 + rbA + rr0)  LOADB(RbB, y0 + 1 + rbB + rr0) \
      EMITA(rbA + rr0 + 2, RcA, RaA, RbA, CHK)  EMITB(rbB + rr0 + 2, RcB, RaB, RbB, CHK) \
    } }

    if (inter) PH1LOOP(0) else PH1LOOP(1)

#undef LOADA
#undef LOADB
#undef EMITG
#undef EMITA
#undef EMITB
#undef PH1LOOP
  }
  __syncthreads();

  // phase 2: MFMA GEMM, 16x16x32_bf16 only, A double-buffered
  int wv = tid >> 6, lane = tid & 63;
  int tx = lane & 15, gq = lane >> 4;
  f32x4 acc[4][3];
#pragma unroll
  for (int nn = 0; nn < 4; ++nn)
#pragma unroll
    for (int m = 0; m < 3; ++m) acc[nn][m] = (f32x4){0.f, 0.f, 0.f, 0.f};

  const unsigned short* abase = wbf64 + (tx)*64;
  bf16x8 Ac0[3], Ac1[3], An0[3], An1[3];
#pragma unroll
  for (int m = 0; m < 3; ++m) {
    const unsigned short* ap = abase + (m * 16) * 64;
    Ac0[m] = *(const bf16x8*)(ap + gq * 8);
    Ac1[m] = *(const bf16x8*)(ap + 32 + gq * 8);
  }

  for (int k = 0; k < 9; ++k) {
    if (k < 8) {
#pragma unroll
      for (int m = 0; m < 3; ++m) {
        const unsigned short* ap = abase + ((k + 1) * 48 + m * 16) * 64;
        An0[m] = *(const bf16x8*)(ap + gq * 8);
        An1[m] = *(const bf16x8*)(ap + 32 + gq * 8);
      }
    }
    int dy = k / 3, dx = k - dy * 3;
#pragma unroll
    for (int nn = 0; nn < 4; ++nn) {
      int n = wv * 4 + nn;
      const short* bp = XF + ((n + dy) * 18 + tx + dx) * XFP;
      bf16x8 B0 = *(const bf16x8*)(bp + gq * 8);
      bf16x8 B1 = *(const bf16x8*)(bp + 32 + gq * 8);  // pad/next-row, A=0 there
#pragma unroll
      for (int m = 0; m < 3; ++m) {
        acc[nn][m] = __builtin_amdgcn_mfma_f32_16x16x32_bf16(Ac0[m], B0, acc[nn][m], 0, 0, 0);
        acc[nn][m] = __builtin_amdgcn_mfma_f32_16x16x32_bf16(Ac1[m], B1, acc[nn][m], 0, 0, 0);
      }
    }
#pragma unroll
    for (int m = 0; m < 3; ++m) { Ac0[m] = An0[m]; Ac1[m] = An1[m]; }
  }

  // epilogue: C frag col=lane&15 (pixel x), row=gq*4+r (oc)
#pragma unroll
  for (int nn = 0; nn < 4; ++nn) {
    int y = y0 + wv * 4 + nn;
#pragma unroll
    for (int m = 0; m < 3; ++m) {
#pragma unroll
      for (int r = 0; r < 4; ++r) {
        int oc = m * 16 + gq * 4 + r;
        out[((size_t)(o * COUT + oc) << 14) + (y << 7) + x0 + tx] = acc[nn][m][r];
      }
    }
  }
}

// ---------------------------------------------------------------------------
extern "C" void kernel_launch(void* const* d_in, const int* in_sizes, int n_in,
                              void* d_out, int out_size, void* d_ws, size_t ws_size,
                              hipStream_t stream)
{
  const float* x      = (const float*)d_in[0];
  const float* freq   = (const float*)d_in[1];
  const float* theta  = (const float*)d_in[2];
  const float* sigma  = (const float*)d_in[3];
  const float* psi    = (const float*)d_in[4];
  const float* f0     = (const float*)d_in[5];
  const float* theta0 = (const float*)d_in[6];
  float* out = (float*)d_out;
  float* ws  = (float*)d_ws;

  float*  w     = ws;
  float*  ar    = ws + 20736;
  float*  ai    = ws + 20864;
  float2* Up    = (float2*)(ws + OFF_UP);
  float*  yf    = ws + OFF_YF;
  unsigned short* wbf64 = (unsigned short*)(ws + OFF_WBF64);

  gabor_k<<<dim3(81), dim3(256), 0, stream>>>(freq, theta, sigma, psi, f0, theta0, w, wbf64);
  circ_k<<<dim3(1), dim3(128), 0, stream>>>(ar, ai);
  stage1_k<<<dim3(16, 48), dim3(256), 0, stream>>>(x, ar, ai, Up);
  stage2_k<<<dim3(16, 48), dim3(256), 0, stream>>>(Up, ar, ai, yf);
  conv2_k<<<dim3(8, 8, 48), dim3(256), 0, stream>>>(yf, w, wbf64, out);
}

// Round 24
// 153.852 us; speedup vs baseline: 1.4488x; 1.0150x over previous
//
#include <hip/hip_runtime.h>

#define CIN 48
#define COUT 48
#define NPIX 16384  // 128*128
#define XFP 52      // XF pitch in shorts (104 B): bank conflicts 5.8M -> 0.88M (R11/R12)
#define YROW 6144   // 48*128: yf stored [y][i][x]

typedef float f32x4 __attribute__((ext_vector_type(4)));
typedef short bf16x8 __attribute__((ext_vector_type(8)));

__device__ __forceinline__ unsigned short f2bf(float f) {
  unsigned u = __float_as_uint(f);
  unsigned r = (u + 0x7FFFu + ((u >> 16) & 1u)) >> 16;  // RNE
  return (unsigned short)r;
}

// packed f32x2 -> bf16x2 in one VALU op (gfx950; no builtin -- inline asm)
__device__ __forceinline__ unsigned cvtpk_bf16(float lo, float hi) {
  unsigned r;
  asm("v_cvt_pk_bf16_f32 %0, %1, %2" : "=v"(r) : "v"(lo), "v"(hi));
  return r;
}

// ws layout (floats):
//   w[20736] | ar[128] | ai[128] | pad->21248 | Up[1572864] | yf[786432] | wbf64[13824]
#define OFF_UP     21248
#define OFF_YF     (OFF_UP + CIN * NPIX * 2)
#define OFF_WBF64  (OFF_YF + CIN * NPIX)

// ---------------------------------------------------------------------------
// K1: Gabor weights. f32 w[oc][i][9]; bf16 A-table wbf64[(k*48+oc)*64+i],
//     i pad [48,64) zeroed.
// ---------------------------------------------------------------------------
__global__ __launch_bounds__(256) void gabor_k(
    const float* __restrict__ freq, const float* __restrict__ theta,
    const float* __restrict__ sigma, const float* __restrict__ psi,
    const float* __restrict__ f0, const float* __restrict__ theta0,
    float* __restrict__ wout, unsigned short* __restrict__ wbf64)
{
  int idx = blockIdx.x * 256 + threadIdx.x;
  if (idx < 432 * 16) {
    wbf64[(idx >> 4) * 64 + 48 + (idx & 15)] = 0;
  }
  if (idx >= COUT * CIN * 9) return;
  int k = idx % 9;
  int oi = idx / 9;
  int oc = oi / CIN, ic = oi % CIN;
  int a = k / 3, b = k % 3;
  float Yv = (a == 0) ? -1.0f : ((a == 1) ? 0.5f : 2.0f);
  float Xv = (b == 0) ? -1.0f : ((b == 1) ? 0.5f : 2.0f);
  float th = theta[oi], sg = sigma[oi], fr = freq[oi], ps = psi[oi];
  float F0 = f0[oi], th0 = theta0[oi];
  float c = cosf(th), s = sinf(th);
  float rotx =  Xv * c + Yv * s;
  float roty = -Xv * s + Yv * c;
  float r = sqrtf(rotx * rotx + roty * roty + 0.001f);
  float denom = 2.0f * logf(sg / F0);
  float t1 = (logf(r) - logf(F0)) / denom;
  float g_rad = expf(-t1 * t1);
  float dth = th - th0;
  float g_ang = expf(-dth * dth / (2.0f * sg * sg));
  float g = g_rad * g_ang * cosf(fr * r + ps) / (6.283185307179586f * sg * sg);
  wout[idx] = g;
  wbf64[(k * 48 + oc) * 64 + ic] = f2bf(g);
}

// ---------------------------------------------------------------------------
// K2: circulant band-limit vector
// ---------------------------------------------------------------------------
__global__ void circ_k(float* __restrict__ ar, float* __restrict__ ai)
{
  int d = threadIdx.x;
  float sr = 0.f, si = 0.f;
  for (int u = 34; u < 94; ++u) {
    int m = (u * d) & 127;
    float ang = (float)m * 0.049087385212340526f;
    sr += cosf(ang);
    si += sinf(ang);
  }
  ar[d] = sr * (1.0f / 128.0f);
  ai[d] = si * (1.0f / 128.0f);
}

// ---------------------------------------------------------------------------
// K3a: row band-limit. grid (16, 48): 8 rows per block.
// ---------------------------------------------------------------------------
__global__ __launch_bounds__(256) void stage1_k(
    const float* __restrict__ x, const float* __restrict__ arr,
    const float* __restrict__ aii, float2* __restrict__ Up)
{
  __shared__ float Xs[8 * 128];
  __shared__ float ars[128], ais[128];
  int yg = blockIdx.x, i = blockIdx.y;
  int t = threadIdx.x;
  const float* Xi = x + i * NPIX + yg * 8 * 128;
  for (int p = t; p < 1024; p += 256) Xs[p] = Xi[p];
  if (t < 128) { ars[t] = arr[t]; ais[t] = aii[t]; }
  __syncthreads();
  int j = t & 127;
  int ysl = t >> 7;
  float accr[4], acci[4];
#pragma unroll
  for (int yy = 0; yy < 4; ++yy) { accr[yy] = 0.f; acci[yy] = 0.f; }
  for (int xx = 0; xx < 128; ++xx) {
    float tr = ars[(j - xx) & 127];
    float ti = ais[(j - xx) & 127];
#pragma unroll
    for (int yy = 0; yy < 4; ++yy) {
      float xv = Xs[(ysl * 4 + yy) * 128 + xx];
      accr[yy] += xv * tr;
      acci[yy] += xv * ti;
    }
  }
  float2* UpI = Up + i * NPIX;
  int ybase = yg * 8 + ysl * 4;
#pragma unroll
  for (int yy = 0; yy < 4; ++yy)
    UpI[(ybase + yy) * 128 + j] = make_float2(accr[yy], acci[yy]);
}

// ---------------------------------------------------------------------------
// K3b: column band-limit. grid (16, 48): 8 cols per block. f32 output,
//  transposed layout yf[y][i][x].
// ---------------------------------------------------------------------------
__global__ __launch_bounds__(256) void stage2_k(
    const float2* __restrict__ Up, const float* __restrict__ arr,
    const float* __restrict__ aii, float* __restrict__ yf)
{
  __shared__ float2 Us[128 * 8];
  __shared__ float ars[128], ais[128];
  int jg = blockIdx.x, i = blockIdx.y;
  int t = threadIdx.x;
  const float2* UpI = Up + i * NPIX;
  for (int p = t; p < 1024; p += 256) {
    int y = p >> 3, jj = p & 7;
    Us[p] = UpI[y * 128 + jg * 8 + jj];
  }
  if (t < 128) { ars[t] = arr[t]; ais[t] = aii[t]; }
  __syncthreads();
  int yp = t & 127;
  int xsl = t >> 7;
  float acc[4];
#pragma unroll
  for (int xx = 0; xx < 4; ++xx) acc[xx] = 0.f;
  for (int y = 0; y < 128; ++y) {
    float tr = ars[(yp - y) & 127];
    float ti = ais[(yp - y) & 127];
#pragma unroll
    for (int xx = 0; xx < 4; ++xx) {
      float2 u = Us[y * 8 + xsl * 4 + xx];
      acc[xx] += u.x * tr - u.y * ti;
    }
  }
  int xb = jg * 8 + xsl * 4;
#pragma unroll
  for (int xx = 0; xx < 4; ++xx)
    yf[(yp * 48 + i) * 128 + xb + xx] = acc[xx];   // [y][i][x]
}

// ---------------------------------------------------------------------------
// K4 (R23 + nontemporal out stores):
//  fused stencil + MFMA GEMM, (256,3) = proven 84-VGPR no-spill equilibrium.
//  LDS: XF[324 px][52 shorts] + 16-short zero tail = 33728 B.
//  NaN invariant: pad [48,52) + tail zeroed; B1 spill reads -> next row's
//  i<16 x A-cols 48..63 = 0, or row 323 -> zeroed tail.
//  Phase 1: 480 half-strip tasks, threads 0..239 run 2 interleaved;
//  interior tiles skip bounds checks; bf16 convert via v_cvt_pk_bf16_f32.
//  Phase 2: 16x16x32_bf16 only; A zero-padded i>=48; A double-buffered.
//  Epilogue: NT stores (out is a 151MB write-once stream; keep L2 for yf).
// ---------------------------------------------------------------------------
__global__ __launch_bounds__(256, 3) void conv2_k(
    const float* __restrict__ yf, const float* __restrict__ wts,
    const unsigned short* __restrict__ wbf64, float* __restrict__ out)
{
  __shared__ __align__(16) short XF[324 * XFP + 16];

  int o  = blockIdx.z;
  int y0 = blockIdx.y * 16, x0 = blockIdx.x * 16;
  int tid = threadIdx.x;

  // phase 0: zero per-row pad shorts [48,52) and tail (NaN invariant)
  for (int p = tid; p < 324; p += 256)
    *(uint2*)(XF + p * XFP + 48) = make_uint2(0u, 0u);
  if (tid < 16) XF[324 * XFP + tid] = 0;

  // phase 1: xf(y,x) = sum_{dy,dx in 0..2} w[dy,dx] * yf((y-dy)&127,(x-dx)&127)
  bool inter = (y0 >= 16) && (y0 <= 96) && (x0 >= 16) && (x0 <= 96);
  if (tid < 240) {
    int sA = tid, sB = tid + 240;
    int iA = sA / 10, rA = sA - iA * 10, spA = rA % 5, hA = rA / 5;
    int iB = sB / 10, rB = sB - iB * 10, spB = rB % 5, hB = rB / 5;
    const float* WpA = wts + (o * CIN + iA) * 9;
    const float* WpB = wts + (o * CIN + iB) * 9;
    float WA0 = WpA[0], WA1 = WpA[1], WA2 = WpA[2], WA3 = WpA[3], WA4 = WpA[4],
          WA5 = WpA[5], WA6 = WpA[6], WA7 = WpA[7], WA8 = WpA[8];
    float WB0 = WpB[0], WB1 = WpB[1], WB2 = WpB[2], WB3 = WpB[3], WB4 = WpB[4],
          WB5 = WpB[5], WB6 = WpB[6], WB7 = WpB[7], WB8 = WpB[8];
    const float* yfA = yf + iA * 128;   // [y][i][x]: plane base = i*128
    const float* yfB = yf + iB * 128;
    int cbA = (x0 - 4 + 4 * spA) & 127;
    int cbB = (x0 - 4 + 4 * spB) & 127;
    int rbA = hA * 9, rbB = hB * 9;
    float RaA[8], RbA[8], RcA[8], RaB[8], RbB[8], RcB[8];

#define LOADA(dst, ry) { \
    const float* rp_ = yfA + ((ry) & 127) * YROW; \
    float4 q0_ = *(const float4*)(rp_ + cbA); \
    float4 q1_ = *(const float4*)(rp_ + ((cbA + 4) & 127)); \
    dst[0]=q0_.x; dst[1]=q0_.y; dst[2]=q0_.z; dst[3]=q0_.w; \
    dst[4]=q1_.x; dst[5]=q1_.y; dst[6]=q1_.z; dst[7]=q1_.w; }
#define LOADB(dst, ry) { \
    const float* rp_ = yfB + ((ry) & 127) * YROW; \
    float4 q0_ = *(const float4*)(rp_ + cbB); \
    float4 q1_ = *(const float4*)(rp_ + ((cbB + 4) & 127)); \
    dst[0]=q0_.x; dst[1]=q0_.y; dst[2]=q0_.z; dst[3]=q0_.w; \
    dst[4]=q1_.x; dst[5]=q1_.y; dst[6]=q1_.z; dst[7]=q1_.w; }

// compute 4 px, pack 2x cvt_pk, store the (cidx<18) ones
#define EMITG(rr, R2_, R1_, R0_, W0_,W1_,W2_,W3_,W4_,W5_,W6_,W7_,W8_, SP_, II_, CHK) { \
    int y_ = y0 - 1 + (rr); \
    float v_[4]; \
    _Pragma("unroll") \
    for (int j = 0; j < 4; ++j) { \
      v_[j] = W0_ * R0_[j + 3] + W1_ * R0_[j + 2] + W2_ * R0_[j + 1] \
            + W3_ * R1_[j + 3] + W4_ * R1_[j + 2] + W5_ * R1_[j + 1] \
            + W6_ * R2_[j + 3] + W7_ * R2_[j + 2] + W8_ * R2_[j + 1]; \
      if (CHK) { \
        int xg_ = x0 - 1 + 4 * SP_ + j; \
        if (!((y_ >= 0) && (y_ < 128) && (xg_ >= 0) && (xg_ < 128))) v_[j] = 0.f; \
      } \
    } \
    unsigned p01_ = cvtpk_bf16(v_[0], v_[1]); \
    unsigned p23_ = cvtpk_bf16(v_[2], v_[3]); \
    short* base_ = XF + ((rr) * 18 + 4 * SP_) * XFP + II_; \
    base_[0]       = (short)(p01_ & 0xffffu); \
    base_[XFP]     = (short)(p01_ >> 16); \
    if (4 * SP_ + 2 < 18) { \
      base_[2 * XFP] = (short)(p23_ & 0xffffu); \
      base_[3 * XFP] = (short)(p23_ >> 16); \
    } }

#define EMITA(rr, R2_, R1_, R0_, CHK) \
    EMITG(rr, R2_, R1_, R0_, WA0,WA1,WA2,WA3,WA4,WA5,WA6,WA7,WA8, spA, iA, CHK)
#define EMITB(rr, R2_, R1_, R0_, CHK) \
    EMITG(rr, R2_, R1_, R0_, WB0,WB1,WB2,WB3,WB4,WB5,WB6,WB7,WB8, spB, iB, CHK)

#define PH1LOOP(CHK) { \
    LOADA(RaA, y0 - 3 + rbA)  LOADB(RaB, y0 - 3 + rbB) \
    LOADA(RbA, y0 - 2 + rbA)  LOADB(RbB, y0 - 2 + rbB) \
    _Pragma("unroll") \
    for (int rr0 = 0; rr0 < 9; rr0 += 3) { \
      LOADA(RcA, y0 - 1 + rbA + rr0)  LOADB(RcB, y0 - 1 + rbB + rr0) \
      EMITA(rbA + rr0,     RaA, RbA, RcA, CHK)  EMITB(rbB + rr0,     RaB, RbB, RcB, CHK) \
      LOADA(RaA, y0 + rbA + rr0)      LOADB(RaB, y0 + rbB + rr0) \
      EMITA(rbA + rr0 + 1, RbA, RcA, RaA, CHK)  EMITB(rbB + rr0 + 1, RbB, RcB, RaB, CHK) \
      LOADA(RbA, y0 + 1 + rbA + rr0)  LOADB(RbB, y0 + 1 + rbB + rr0) \
      EMITA(rbA + rr0 + 2, RcA, RaA, RbA, CHK)  EMITB(rbB + rr0 + 2, RcB, RaB, RbB, CHK) \
    } }

    if (inter) PH1LOOP(0) else PH1LOOP(1)

#undef LOADA
#undef LOADB
#undef EMITG
#undef EMITA
#undef EMITB
#undef PH1LOOP
  }
  __syncthreads();

  // phase 2: MFMA GEMM, 16x16x32_bf16 only, A double-buffered
  int wv = tid >> 6, lane = tid & 63;
  int tx = lane & 15, gq = lane >> 4;
  f32x4 acc[4][3];
#pragma unroll
  for (int nn = 0; nn < 4; ++nn)
#pragma unroll
    for (int m = 0; m < 3; ++m) acc[nn][m] = (f32x4){0.f, 0.f, 0.f, 0.f};

  const unsigned short* abase = wbf64 + (tx)*64;
  bf16x8 Ac0[3], Ac1[3], An0[3], An1[3];
#pragma unroll
  for (int m = 0; m < 3; ++m) {
    const unsigned short* ap = abase + (m * 16) * 64;
    Ac0[m] = *(const bf16x8*)(ap + gq * 8);
    Ac1[m] = *(const bf16x8*)(ap + 32 + gq * 8);
  }

  for (int k = 0; k < 9; ++k) {
    if (k < 8) {
#pragma unroll
      for (int m = 0; m < 3; ++m) {
        const unsigned short* ap = abase + ((k + 1) * 48 + m * 16) * 64;
        An0[m] = *(const bf16x8*)(ap + gq * 8);
        An1[m] = *(const bf16x8*)(ap + 32 + gq * 8);
      }
    }
    int dy = k / 3, dx = k - dy * 3;
#pragma unroll
    for (int nn = 0; nn < 4; ++nn) {
      int n = wv * 4 + nn;
      const short* bp = XF + ((n + dy) * 18 + tx + dx) * XFP;
      bf16x8 B0 = *(const bf16x8*)(bp + gq * 8);
      bf16x8 B1 = *(const bf16x8*)(bp + 32 + gq * 8);  // pad/next-row, A=0 there
#pragma unroll
      for (int m = 0; m < 3; ++m) {
        acc[nn][m] = __builtin_amdgcn_mfma_f32_16x16x32_bf16(Ac0[m], B0, acc[nn][m], 0, 0, 0);
        acc[nn][m] = __builtin_amdgcn_mfma_f32_16x16x32_bf16(Ac1[m], B1, acc[nn][m], 0, 0, 0);
      }
    }
#pragma unroll
    for (int m = 0; m < 3; ++m) { Ac0[m] = An0[m]; Ac1[m] = An1[m]; }
  }

  // epilogue: C frag col=lane&15 (pixel x), row=gq*4+r (oc); NT stores
#pragma unroll
  for (int nn = 0; nn < 4; ++nn) {
    int y = y0 + wv * 4 + nn;
#pragma unroll
    for (int m = 0; m < 3; ++m) {
#pragma unroll
      for (int r = 0; r < 4; ++r) {
        int oc = m * 16 + gq * 4 + r;
        __builtin_nontemporal_store(acc[nn][m][r],
            &out[((size_t)(o * COUT + oc) << 14) + (y << 7) + x0 + tx]);
      }
    }
  }
}

// ---------------------------------------------------------------------------
extern "C" void kernel_launch(void* const* d_in, const int* in_sizes, int n_in,
                              void* d_out, int out_size, void* d_ws, size_t ws_size,
                              hipStream_t stream)
{
  const float* x      = (const float*)d_in[0];
  const float* freq   = (const float*)d_in[1];
  const float* theta  = (const float*)d_in[2];
  const float* sigma  = (const float*)d_in[3];
  const float* psi    = (const float*)d_in[4];
  const float* f0     = (const float*)d_in[5];
  const float* theta0 = (const float*)d_in[6];
  float* out = (float*)d_out;
  float* ws  = (float*)d_ws;

  float*  w     = ws;
  float*  ar    = ws + 20736;
  float*  ai    = ws + 20864;
  float2* Up    = (float2*)(ws + OFF_UP);
  float*  yf    = ws + OFF_YF;
  unsigned short* wbf64 = (unsigned short*)(ws + OFF_WBF64);

  gabor_k<<<dim3(81), dim3(256), 0, stream>>>(freq, theta, sigma, psi, f0, theta0, w, wbf64);
  circ_k<<<dim3(1), dim3(128), 0, stream>>>(ar, ai);
  stage1_k<<<dim3(16, 48), dim3(256), 0, stream>>>(x, ar, ai, Up);
  stage2_k<<<dim3(16, 48), dim3(256), 0, stream>>>(Up, ar, ai, yf);
  conv2_k<<<dim3(8, 8, 48), dim3(256), 0, stream>>>(yf, w, wbf64, out);
}